// Round 11
// baseline (128.052 us; speedup 1.0000x reference)
//
#include <hip/hip_runtime.h>

#define B_  64
#define F_  64
#define NC_ 27
#define L_  1024
#define EPSV 1e-5f
#define NCHUNK 8

typedef __bf16 bf16x8 __attribute__((ext_vector_type(8)));
typedef float  f32x4  __attribute__((ext_vector_type(4)));

static __device__ __forceinline__ float relu_(float v) { return fmaxf(v, 0.f); }
static __device__ __forceinline__ ushort f2bf(float f) {
    __bf16 h = (__bf16)f;
    ushort r;
    __builtin_memcpy(&r, &h, 2);
    return r;
}
static __device__ __forceinline__ float bf2f(ushort u) {
    __bf16 h;
    __builtin_memcpy(&h, &u, 2);
    return (float)h;
}
static __device__ __forceinline__ bf16x8 cvt8(float4 a, float4 b) {
    bf16x8 r;
    r[0] = (__bf16)a.x; r[1] = (__bf16)a.y; r[2] = (__bf16)a.z; r[3] = (__bf16)a.w;
    r[4] = (__bf16)b.x; r[5] = (__bf16)b.y; r[6] = (__bf16)b.z; r[7] = (__bf16)b.w;
    return r;
}

// ================= K_A (mega): blocks 0..511 per-(b, 128-l tile):
//   softmax+pool -> sP + Pt ; MFMA trans -> yb16 + sT/sTt ; MFMA yw -> ywb ;
//   MFMA partial U/yn -> intra-block 4-wave LDS reduce -> 1 chunk per block (NCHUNK=8)
// blocks 512..1535 : adj -> bf16 ; block 1536 : back_w*bn2_scale -> bf16
__global__ __launch_bounds__(256) void k_mega(
    const float* __restrict__ x, const float* __restrict__ SP,
    const float* __restrict__ w, const float* __restrict__ g,
    const float* __restrict__ beta, const float* __restrict__ w_sp,
    const float* __restrict__ w_nc,
    const float* __restrict__ adj, const float* __restrict__ bw,
    const float* __restrict__ g2,
    ushort* __restrict__ Pt, ushort* __restrict__ yb16, ushort* __restrict__ ywb,
    float* __restrict__ partYN, float* __restrict__ partU,
    ushort* __restrict__ adjb, ushort* __restrict__ bwb)
{
    const int blk = blockIdx.x;
    const int t = threadIdx.x;
    if (blk >= 512) {
        if (blk < 1536) {
            int i = (((blk - 512) << 8) + t) << 2;
            float4 v = *(const float4*)(adj + i);
            ushort4 o;
            o.x = f2bf(v.x); o.y = f2bf(v.y); o.z = f2bf(v.z); o.w = f2bf(v.w);
            *(ushort4*)(adjb + i) = o;
        } else {
            const float rs = 1.f / sqrtf(1.f + EPSV);
            for (int j = t; j < 4096; j += 256) {
                int o = j >> 6;
                bwb[j] = f2bf(bw[j] * g2[o] * rs);
            }
        }
        return;
    }

    __shared__ __align__(16) char pool[47616];
    ushort* sT_  = (ushort*)pool;
    ushort* sTt_ = (ushort*)(pool + 18432);
    ushort* sP_  = (ushort*)(pool + 38912);
    float*  red  = (float*)pool;
#define ST(wv_, l_, f_)  sT_[((wv_) * 32 + (l_)) * 72 + (f_)]
#define STT(wv_, f_, l_) sTt_[((wv_) * 64 + (f_)) * 40 + (l_)]
#define SPD(c_, l_)      sP_[(c_) * 136 + (l_)]

    const int wv = t >> 6, lane = t & 63;
    const int rA = lane & 15, kg = lane >> 4;
    const int b = blk >> 3;
    const int l0 = (blk & 7) << 7;
    const int wl0 = l0 + wv * 32;

    // ---- softmax + 2x2 maxpool ----
    {
        const int ll = t >> 1, sub = t & 1;
        const int ol = l0 + ll;
        const int oi = ol >> 5, oj = ol & 31;
        const float* rp = SP + (size_t)b * NC_ * 4096 + (2 * oi + sub) * 64 + 2 * oj;
        float v0[NC_], v1[NC_];
        float m0 = -1e30f, m1 = -1e30f;
#pragma unroll
        for (int c = 0; c < NC_; ++c) {
            float2 v = *(const float2*)(rp + c * 4096);
            v0[c] = v.x; v1[c] = v.y;
            m0 = fmaxf(m0, v.x); m1 = fmaxf(m1, v.y);
        }
        float s0 = 0.f, s1 = 0.f;
#pragma unroll
        for (int c = 0; c < NC_; ++c) {
            v0[c] = __expf(v0[c] - m0); s0 += v0[c];
            v1[c] = __expf(v1[c] - m1); s1 += v1[c];
        }
        float i0 = 1.f / s0, i1 = 1.f / s1;
        float acc[NC_];
#pragma unroll
        for (int c = 0; c < NC_; ++c) acc[c] = fmaxf(v0[c] * i0, v1[c] * i1);
#pragma unroll
        for (int c = 0; c < NC_; ++c) acc[c] = fmaxf(acc[c], __shfl_xor(acc[c], 1));
        if (!sub) {
            ushort h[32];
#pragma unroll
            for (int c = 0; c < NC_; ++c) { h[c] = f2bf(acc[c]); SPD(c, ll) = h[c]; }
#pragma unroll
            for (int c = NC_; c < 32; ++c) h[c] = 0;
            ushort* pt = Pt + ((size_t)b * L_ + ol) * 32;
#pragma unroll
            for (int c0 = 0; c0 < 32; c0 += 4)
                *(ushort4*)&pt[c0] = *(ushort4*)&h[c0];
        } else {
#pragma unroll
            for (int r = NC_; r < 32; ++r)
                for (int c = ll; c < 136; c += 128) SPD(r, c) = 0;
        }
    }

    // ---- MFMA1: t[l][f] = sum_c x[c][l] * w[f][c] ----
    const float* xb = x + ((size_t)b << 16);
    f32x4 acc[2][4];
#pragma unroll
    for (int i = 0; i < 2; ++i)
#pragma unroll
        for (int j = 0; j < 4; ++j) acc[i][j] = (f32x4){0.f, 0.f, 0.f, 0.f};
#pragma unroll
    for (int ks = 0; ks < 2; ++ks) {
        bf16x8 a[2];
#pragma unroll
        for (int lt = 0; lt < 2; ++lt) {
            const int l = wl0 + lt * 16 + rA;
            bf16x8 av;
#pragma unroll
            for (int j = 0; j < 8; ++j)
                av[j] = (__bf16)xb[(size_t)(ks * 32 + kg * 8 + j) * 1024 + l];
            a[lt] = av;
        }
#pragma unroll
        for (int fc = 0; fc < 4; ++fc) {
            const float* wp = w + (fc * 16 + rA) * 64 + ks * 32 + kg * 8;
            bf16x8 bv = cvt8(*(const float4*)wp, *(const float4*)(wp + 4));
            acc[0][fc] = __builtin_amdgcn_mfma_f32_16x16x32_bf16(a[0], bv, acc[0][fc], 0, 0, 0);
            acc[1][fc] = __builtin_amdgcn_mfma_f32_16x16x32_bf16(a[1], bv, acc[1][fc], 0, 0, 0);
        }
    }

    // ---- epilogue: BN + ReLU ; yb16 global ; sT [l][f] ; sTt [f][l] ----
    const float rs = 1.f / sqrtf(1.f + EPSV);
    ushort* yg = yb16 + ((size_t)b << 16);
#pragma unroll
    for (int fc = 0; fc < 4; ++fc) {
        const int f = fc * 16 + rA;
        const float sc = g[f] * rs, bb = beta[f];
#pragma unroll
        for (int lt = 0; lt < 2; ++lt) {
            ushort4 tv;
            ushort* tp = (ushort*)&tv;
#pragma unroll
            for (int r = 0; r < 4; ++r) {
                float v = relu_(sc * acc[lt][fc][r] + bb);
                tp[r] = f2bf(v);
                ST(wv, lt * 16 + kg * 4 + r, f) = tp[r];
                STT(wv, f, lt * 16 + kg * 4 + r) = tp[r];
            }
            *(ushort4*)(yg + (size_t)f * 1024 + wl0 + lt * 16 + kg * 4) = tv;
        }
    }
    __syncthreads();

    // ---- MFMA2: yw[l][f] = sum_f' t[l][f'] * w_sp[f][f'] ----
    f32x4 acc2[2][4];
#pragma unroll
    for (int i = 0; i < 2; ++i)
#pragma unroll
        for (int j = 0; j < 4; ++j) acc2[i][j] = (f32x4){0.f, 0.f, 0.f, 0.f};
#pragma unroll
    for (int kh = 0; kh < 2; ++kh) {
        bf16x8 a[2];
#pragma unroll
        for (int lt = 0; lt < 2; ++lt)
            a[lt] = *(const bf16x8*)&ST(wv, lt * 16 + rA, kh * 32 + kg * 8);
#pragma unroll
        for (int fc = 0; fc < 4; ++fc) {
            const float* wp = w_sp + (fc * 16 + rA) * 64 + kh * 32 + kg * 8;
            bf16x8 bv = cvt8(*(const float4*)wp, *(const float4*)(wp + 4));
            acc2[0][fc] = __builtin_amdgcn_mfma_f32_16x16x32_bf16(a[0], bv, acc2[0][fc], 0, 0, 0);
            acc2[1][fc] = __builtin_amdgcn_mfma_f32_16x16x32_bf16(a[1], bv, acc2[1][fc], 0, 0, 0);
        }
    }
    ushort* yp = ywb + ((size_t)b << 16);
#pragma unroll
    for (int fc = 0; fc < 4; ++fc) {
        const int f = fc * 16 + rA;
#pragma unroll
        for (int lt = 0; lt < 2; ++lt) {
            ushort4 ov;
            ov.x = f2bf(acc2[lt][fc][0]);
            ov.y = f2bf(acc2[lt][fc][1]);
            ov.z = f2bf(acc2[lt][fc][2]);
            ov.w = f2bf(acc2[lt][fc][3]);
            *(ushort4*)(yp + (size_t)f * 1024 + wl0 + lt * 16 + kg * 4) = ov;
        }
    }

    // ---- per-wave partials: U[c][f] = P·t^T, yn[c][f] = w_nc·t^T (K=32) ----
    f32x4 accU[2][4], accN[2][4];
    {
        const int lw = wv * 32 + kg * 8;
        bf16x8 aU[2], aN[2];
        aU[0] = *(const bf16x8*)&SPD(rA, lw);
        aU[1] = *(const bf16x8*)&SPD(16 + rA, lw);
        {
            const float* w0 = w_nc + (size_t)rA * 1024 + l0 + lw;
            aN[0] = cvt8(*(const float4*)w0, *(const float4*)(w0 + 4));
            if (16 + rA < NC_) {
                const float* w1 = w_nc + (size_t)(16 + rA) * 1024 + l0 + lw;
                aN[1] = cvt8(*(const float4*)w1, *(const float4*)(w1 + 4));
            } else {
                bf16x8 z;
#pragma unroll
                for (int j = 0; j < 8; ++j) z[j] = (__bf16)0.f;
                aN[1] = z;
            }
        }
#pragma unroll
        for (int i = 0; i < 2; ++i)
#pragma unroll
            for (int j = 0; j < 4; ++j) {
                accU[i][j] = (f32x4){0.f, 0.f, 0.f, 0.f};
                accN[i][j] = (f32x4){0.f, 0.f, 0.f, 0.f};
            }
#pragma unroll
        for (int nt = 0; nt < 4; ++nt) {
            bf16x8 bt = *(const bf16x8*)&STT(wv, nt * 16 + rA, kg * 8);
#pragma unroll
            for (int mt = 0; mt < 2; ++mt) {
                accU[mt][nt] = __builtin_amdgcn_mfma_f32_16x16x32_bf16(aU[mt], bt, accU[mt][nt], 0, 0, 0);
                accN[mt][nt] = __builtin_amdgcn_mfma_f32_16x16x32_bf16(aN[mt], bt, accN[mt][nt], 0, 0, 0);
            }
        }
    }

    // ---- intra-block reduce 4 waves -> 1 chunk; chunk = blk & 7 ----
    const int chunk = blk & 7;
    float* pu = partU  + ((size_t)b * NCHUNK + chunk) * (NC_ * 64);
    float* py = partYN + ((size_t)b * NCHUNK + chunk) * (NC_ * 64);
    __syncthreads();
#pragma unroll
    for (int mt = 0; mt < 2; ++mt)
#pragma unroll
        for (int r = 0; r < 4; ++r) {
            const int c = mt * 16 + kg * 4 + r;
            if (c < NC_) {
#pragma unroll
                for (int nt = 0; nt < 4; ++nt)
                    red[wv * 1728 + c * 64 + nt * 16 + rA] = accU[mt][nt][r];
            }
        }
    __syncthreads();
    for (int idx = t; idx < NC_ * 64; idx += 256)
        pu[idx] = red[idx] + red[1728 + idx] + red[2 * 1728 + idx] + red[3 * 1728 + idx];
    __syncthreads();
#pragma unroll
    for (int mt = 0; mt < 2; ++mt)
#pragma unroll
        for (int r = 0; r < 4; ++r) {
            const int c = mt * 16 + kg * 4 + r;
            if (c < NC_) {
#pragma unroll
                for (int nt = 0; nt < 4; ++nt)
                    red[wv * 1728 + c * 64 + nt * 16 + rA] = accN[mt][nt][r];
            }
        }
    __syncthreads();
    for (int idx = t; idx < NC_ * 64; idx += 256)
        py[idx] = red[idx] + red[1728 + idx] + red[2 * 1728 + idx] + red[3 * 1728 + idx];
#undef ST
#undef STT
#undef SPD
}

// ---------------- K4: reduce 8 partials; sigma = yn·w_kc^T + b_kc ; Z = sigma·U ; Zwt bf16 ----------------
__global__ void k_sigma_Z(const float* __restrict__ partYN, const float* __restrict__ partU,
                          const float* __restrict__ b_nc,
                          const float* __restrict__ w_kc, const float* __restrict__ b_kc,
                          const float* __restrict__ w_g, ushort* __restrict__ Zwt)
{
    __shared__ float syn[F_ * NC_];     // [f][c]
    __shared__ float su[NC_ * F_];      // [k][f]
    __shared__ float swkt[F_ * 28];     // w_kc transposed [ff][k], pitch 28
    __shared__ float ssig[NC_ * NC_];   // [c][k]
    __shared__ float sz[NC_ * F_];      // Z [c][f]
    __shared__ float swg[F_ * F_];      // w_g [f][f']
    const int t = threadIdx.x;          // 512
    const int b = blockIdx.x;
    for (int idx = t; idx < NC_ * F_; idx += 512) {
        int c = idx >> 6, f = idx & 63;
        float sy = 0.f, suv = 0.f;
        const float* py = partYN + ((size_t)b * NCHUNK) * (NC_ * 64) + idx;
        const float* pu = partU  + ((size_t)b * NCHUNK) * (NC_ * 64) + idx;
#pragma unroll
        for (int p = 0; p < NCHUNK; ++p) {
            sy  += py[p * (NC_ * 64)];
            suv += pu[p * (NC_ * 64)];
        }
        syn[f * NC_ + c] = sy + b_nc[c];
        su[c * F_ + f]   = suv;
    }
    for (int idx = t; idx < NC_ * F_; idx += 512) {
        int k = idx >> 6, ff = idx & 63;
        swkt[ff * 28 + k] = w_kc[idx];
    }
    for (int idx = t; idx < F_ * F_; idx += 512) swg[idx] = w_g[idx];
    __syncthreads();
    for (int idx = t; idx < NC_ * NC_; idx += 512) {
        int c = idx / NC_, k = idx - c * NC_;
        float s = b_kc[k];
        for (int ff = 0; ff < F_; ++ff)
            s = fmaf(syn[ff * NC_ + c], swkt[ff * 28 + k], s);
        ssig[c * NC_ + k] = s;
    }
    __syncthreads();
    for (int idx = t; idx < NC_ * F_; idx += 512) {
        int c = idx >> 6, ff = idx & 63;
        float s = 0.f;
        for (int k = 0; k < NC_; ++k)
            s = fmaf(ssig[c * NC_ + k], su[k * F_ + ff], s);
        sz[idx] = s;
    }
    __syncthreads();
    for (int idx = t; idx < F_ * 32; idx += 512) {
        int f = idx >> 5, c = idx & 31;
        float s = 0.f;
        if (c < NC_)
            for (int fp = 0; fp < F_; ++fp)
                s = fmaf(sz[c * F_ + fp], swg[f * F_ + fp], s);
        Zwt[(size_t)b * F_ * 32 + idx] = f2bf(s);
    }
}

// ---------------- K5: MFMA fused, 64-row tiles, LDS-FREE main GEMM (operands stream from L2) ----------------
__global__ __launch_bounds__(256, 4) void k_fused2(
    const ushort* __restrict__ adjb_, const ushort* __restrict__ ywb_,
    const ushort* __restrict__ Pt_, const ushort* __restrict__ Zwt_,
    const ushort* __restrict__ yb16, const float* __restrict__ b_g,
    const float* __restrict__ b_sp, const ushort* __restrict__ bwb_,
    const float* __restrict__ bn2b, float* __restrict__ out)
{
    __shared__ __align__(16) float sPre[64 * 68];   // 17408 B (epilogue handoff only)

    const int t = threadIdx.x;
    const int w = t >> 6, lane = t & 63;
    const int rA = lane & 15, kg = lane >> 4;
    const int b = blockIdx.x >> 4;
    const int l0 = (blockIdx.x & 15) << 6;          // 64-row tile
    const int wl0 = l0 + w * 16;                    // this wave's 16 rows

    const __bf16* adjb = (const __bf16*)adjb_;
    const __bf16* ywb  = (const __bf16*)ywb_ + ((size_t)b << 16);
    const __bf16* Ptb  = (const __bf16*)Pt_  + ((size_t)b << 15);
    const __bf16* Zwtb = (const __bf16*)Zwt_ + ((size_t)b << 11);
    const __bf16* bwb  = (const __bf16*)bwb_;

    // ---- main GEMM: S[l][f] = sum_m adj[l][m] * yw[f][m] — both operands direct from L2 ----
    f32x4 accS[4];
#pragma unroll
    for (int j = 0; j < 4; ++j) accS[j] = (f32x4){0.f, 0.f, 0.f, 0.f};

    const __bf16* pa = adjb + (size_t)(wl0 + rA) * 1024 + kg * 8;
    const __bf16* pb = ywb + (size_t)rA * 1024 + kg * 8;

#pragma unroll 4
    for (int ks = 0; ks < 32; ++ks) {
        bf16x8 a0 = *(const bf16x8*)(pa + ks * 32);
        bf16x8 f0 = *(const bf16x8*)(pb + 0 * 16384 + ks * 32);
        bf16x8 f1 = *(const bf16x8*)(pb + 1 * 16384 + ks * 32);
        bf16x8 f2 = *(const bf16x8*)(pb + 2 * 16384 + ks * 32);
        bf16x8 f3 = *(const bf16x8*)(pb + 3 * 16384 + ks * 32);
        accS[0] = __builtin_amdgcn_mfma_f32_16x16x32_bf16(a0, f0, accS[0], 0, 0, 0);
        accS[1] = __builtin_amdgcn_mfma_f32_16x16x32_bf16(a0, f1, accS[1], 0, 0, 0);
        accS[2] = __builtin_amdgcn_mfma_f32_16x16x32_bf16(a0, f2, accS[2], 0, 0, 0);
        accS[3] = __builtin_amdgcn_mfma_f32_16x16x32_bf16(a0, f3, accS[3], 0, 0, 0);
    }

    // ---- dynamic path: D[l][f] = sum_c Pt[l][c] * Zwt[f][c], K=32 (c padded) ----
    f32x4 accD[4];
#pragma unroll
    for (int j = 0; j < 4; ++j) accD[j] = (f32x4){0.f, 0.f, 0.f, 0.f};
    {
        const __bf16* qa = Ptb + (size_t)(wl0 + rA) * 32 + kg * 8;
        bf16x8 a0 = *(const bf16x8*)(qa);
        const __bf16* qb = Zwtb + (size_t)rA * 32 + kg * 8;
        bf16x8 z0 = *(const bf16x8*)(qb + 0 * 512);
        bf16x8 z1 = *(const bf16x8*)(qb + 1 * 512);
        bf16x8 z2 = *(const bf16x8*)(qb + 2 * 512);
        bf16x8 z3 = *(const bf16x8*)(qb + 3 * 512);
        accD[0] = __builtin_amdgcn_mfma_f32_16x16x32_bf16(a0, z0, accD[0], 0, 0, 0);
        accD[1] = __builtin_amdgcn_mfma_f32_16x16x32_bf16(a0, z1, accD[1], 0, 0, 0);
        accD[2] = __builtin_amdgcn_mfma_f32_16x16x32_bf16(a0, z2, accD[2], 0, 0, 0);
        accD[3] = __builtin_amdgcn_mfma_f32_16x16x32_bf16(a0, z3, accD[3], 0, 0, 0);
    }

    // ---- epilogue: pre = relu(D + b_g) + relu(S + b_sp) + 3*y -> sPre [64][68] ----
    const ushort* yb = yb16 + ((size_t)b << 16);
    const int wOff = w * 16 * 68;
#pragma unroll
    for (int fc = 0; fc < 4; ++fc) {
        const int f = fc * 16 + rA;
        const float bg = b_g[f], bs = b_sp[f];
        const int lbase = wl0 + kg * 4;
        const int row = kg * 4;
        ushort4 uy = *(const ushort4*)(yb + (size_t)f * 1024 + lbase);
        const float ya[4] = {bf2f(uy.x), bf2f(uy.y), bf2f(uy.z), bf2f(uy.w)};
        f32x4 s = accS[fc], d = accD[fc];
        sPre[wOff + (row + 0) * 68 + f] = relu_(d[0] + bg) + relu_(s[0] + bs) + 3.f * ya[0];
        sPre[wOff + (row + 1) * 68 + f] = relu_(d[1] + bg) + relu_(s[1] + bs) + 3.f * ya[1];
        sPre[wOff + (row + 2) * 68 + f] = relu_(d[2] + bg) + relu_(s[2] + bs) + 3.f * ya[2];
        sPre[wOff + (row + 3) * 68 + f] = relu_(d[3] + bg) + relu_(s[3] + bs) + 3.f * ya[3];
    }
    __syncthreads();

    // ---- back conv: out[o][l] = relu( sum_f pre[l][f] * bwb[o][f] + bn2b[o] ) ----
    f32x4 accO[4];
#pragma unroll
    for (int j = 0; j < 4; ++j) accO[j] = (f32x4){0.f, 0.f, 0.f, 0.f};
#pragma unroll
    for (int kh = 0; kh < 2; ++kh) {
        const int off = wOff + rA * 68 + kh * 32 + kg * 8;
        float4 u0 = *(const float4*)&sPre[off];
        float4 u1 = *(const float4*)&sPre[off + 4];
        bf16x8 af;
        af[0] = (__bf16)u0.x; af[1] = (__bf16)u0.y; af[2] = (__bf16)u0.z; af[3] = (__bf16)u0.w;
        af[4] = (__bf16)u1.x; af[5] = (__bf16)u1.y; af[6] = (__bf16)u1.z; af[7] = (__bf16)u1.w;
#pragma unroll
        for (int oc = 0; oc < 4; ++oc) {
            bf16x8 bo = *(const bf16x8*)(bwb + oc * 1024 + (size_t)rA * 64 + kh * 32 + kg * 8);
            accO[oc] = __builtin_amdgcn_mfma_f32_16x16x32_bf16(af, bo, accO[oc], 0, 0, 0);
        }
    }
    float* ob = out + ((size_t)b << 16);
#pragma unroll
    for (int oc = 0; oc < 4; ++oc) {
        float b2v = bn2b[oc * 16 + rA];
        float4 ov = make_float4(accO[oc][0] + b2v, accO[oc][1] + b2v,
                                accO[oc][2] + b2v, accO[oc][3] + b2v);
        ov.x = relu_(ov.x); ov.y = relu_(ov.y); ov.z = relu_(ov.z); ov.w = relu_(ov.w);
        *(float4*)(ob + (size_t)(oc * 16 + rA) * 1024 + wl0 + kg * 4) = ov;
    }
}

extern "C" void kernel_launch(void* const* d_in, const int* in_sizes, int n_in,
                              void* d_out, int out_size, void* d_ws, size_t ws_size,
                              hipStream_t stream)
{
    const float* x       = (const float*)d_in[0];
    const float* SP      = (const float*)d_in[1];
    const float* trans_w = (const float*)d_in[2];
    const float* bn1_g   = (const float*)d_in[3];
    const float* bn1_b   = (const float*)d_in[4];
    const float* w_nc    = (const float*)d_in[5];
    const float* b_nc    = (const float*)d_in[6];
    const float* w_kc    = (const float*)d_in[7];
    const float* b_kc    = (const float*)d_in[8];
    const float* w_g     = (const float*)d_in[9];
    const float* b_g     = (const float*)d_in[10];
    const float* adj     = (const float*)d_in[11];
    const float* w_sp    = (const float*)d_in[12];
    const float* b_sp    = (const float*)d_in[13];
    const float* back_w  = (const float*)d_in[14];
    const float* bn2_g   = (const float*)d_in[15];
    const float* bn2_b   = (const float*)d_in[16];
    float* out = (float*)d_out;

    float* ws = (float*)d_ws;
    float* partYN = ws;                                     // [B*8][27*64] fp32
    float* partU  = partYN + (size_t)B_ * NCHUNK * NC_ * F_;// [B*8][27*64] fp32
    ushort* Pt   = (ushort*)(partU + (size_t)B_ * NCHUNK * NC_ * F_); // [64][1024][32] bf16
    ushort* Zwt  = Pt   + (size_t)B_ * L_ * 32;             // [64][64][32] bf16
    ushort* yb16 = Zwt  + (size_t)B_ * F_ * 32;             // [64][64][1024] bf16
    ushort* ywb  = yb16 + (size_t)B_ * F_ * L_;             // [64][64][1024] bf16
    ushort* adjb = ywb  + (size_t)B_ * F_ * L_;             // [1024][1024] bf16
    ushort* bwb  = adjb + (size_t)L_ * L_;                  // [64][64] bf16

    k_mega<<<1537, 256, 0, stream>>>(x, SP, trans_w, bn1_g, bn1_b, w_sp, w_nc,
                                     adj, back_w, bn2_g,
                                     Pt, yb16, ywb, partYN, partU, adjb, bwb);
    k_sigma_Z<<<64, 512, 0, stream>>>(partYN, partU, b_nc, w_kc, b_kc, w_g, Zwt);
    k_fused2<<<1024, 256, 0, stream>>>(adjb, ywb, Pt, Zwt, yb16, b_g, b_sp, bwb, bn2_b, out);
}

// Round 12
// 79.253 us; speedup vs baseline: 1.6157x; 1.6157x over previous
//
#include <hip/hip_runtime.h>

#define B_  64
#define F_  64
#define NC_ 27
#define L_  1024
#define EPSV 1e-5f
#define NCHUNK 8

typedef __bf16 bf16x8 __attribute__((ext_vector_type(8)));
typedef float  f32x4  __attribute__((ext_vector_type(4)));

static __device__ __forceinline__ float relu_(float v) { return fmaxf(v, 0.f); }
static __device__ __forceinline__ ushort f2bf(float f) {
    __bf16 h = (__bf16)f;
    ushort r;
    __builtin_memcpy(&r, &h, 2);
    return r;
}
static __device__ __forceinline__ float bf2f(ushort u) {
    __bf16 h;
    __builtin_memcpy(&h, &u, 2);
    return (float)h;
}
static __device__ __forceinline__ bf16x8 cvt8(float4 a, float4 b) {
    bf16x8 r;
    r[0] = (__bf16)a.x; r[1] = (__bf16)a.y; r[2] = (__bf16)a.z; r[3] = (__bf16)a.w;
    r[4] = (__bf16)b.x; r[5] = (__bf16)b.y; r[6] = (__bf16)b.z; r[7] = (__bf16)b.w;
    return r;
}

// ================= K_A (mega): blocks 0..511 per-(b, 128-l tile):
//   softmax+pool -> sP + Pt ; MFMA trans -> yb16 + sT/sTt ; MFMA yw -> ywb ;
//   MFMA partial U/yn -> intra-block 4-wave LDS reduce -> 1 chunk per block (NCHUNK=8)
// blocks 512..1535 : adj -> bf16 ; block 1536 : back_w*bn2_scale -> bf16
__global__ __launch_bounds__(256) void k_mega(
    const float* __restrict__ x, const float* __restrict__ SP,
    const float* __restrict__ w, const float* __restrict__ g,
    const float* __restrict__ beta, const float* __restrict__ w_sp,
    const float* __restrict__ w_nc,
    const float* __restrict__ adj, const float* __restrict__ bw,
    const float* __restrict__ g2,
    ushort* __restrict__ Pt, ushort* __restrict__ yb16, ushort* __restrict__ ywb,
    float* __restrict__ partYN, float* __restrict__ partU,
    ushort* __restrict__ adjb, ushort* __restrict__ bwb)
{
    const int blk = blockIdx.x;
    const int t = threadIdx.x;
    if (blk >= 512) {
        if (blk < 1536) {
            int i = (((blk - 512) << 8) + t) << 2;
            float4 v = *(const float4*)(adj + i);
            ushort4 o;
            o.x = f2bf(v.x); o.y = f2bf(v.y); o.z = f2bf(v.z); o.w = f2bf(v.w);
            *(ushort4*)(adjb + i) = o;
        } else {
            const float rs = 1.f / sqrtf(1.f + EPSV);
            for (int j = t; j < 4096; j += 256) {
                int o = j >> 6;
                bwb[j] = f2bf(bw[j] * g2[o] * rs);
            }
        }
        return;
    }

    __shared__ __align__(16) char pool[47616];
    ushort* sT_  = (ushort*)pool;
    ushort* sTt_ = (ushort*)(pool + 18432);
    ushort* sP_  = (ushort*)(pool + 38912);
    float*  red  = (float*)pool;
#define ST(wv_, l_, f_)  sT_[((wv_) * 32 + (l_)) * 72 + (f_)]
#define STT(wv_, f_, l_) sTt_[((wv_) * 64 + (f_)) * 40 + (l_)]
#define SPD(c_, l_)      sP_[(c_) * 136 + (l_)]

    const int wv = t >> 6, lane = t & 63;
    const int rA = lane & 15, kg = lane >> 4;
    const int b = blk >> 3;
    const int l0 = (blk & 7) << 7;
    const int wl0 = l0 + wv * 32;

    // ---- softmax + 2x2 maxpool ----
    {
        const int ll = t >> 1, sub = t & 1;
        const int ol = l0 + ll;
        const int oi = ol >> 5, oj = ol & 31;
        const float* rp = SP + (size_t)b * NC_ * 4096 + (2 * oi + sub) * 64 + 2 * oj;
        float v0[NC_], v1[NC_];
        float m0 = -1e30f, m1 = -1e30f;
#pragma unroll
        for (int c = 0; c < NC_; ++c) {
            float2 v = *(const float2*)(rp + c * 4096);
            v0[c] = v.x; v1[c] = v.y;
            m0 = fmaxf(m0, v.x); m1 = fmaxf(m1, v.y);
        }
        float s0 = 0.f, s1 = 0.f;
#pragma unroll
        for (int c = 0; c < NC_; ++c) {
            v0[c] = __expf(v0[c] - m0); s0 += v0[c];
            v1[c] = __expf(v1[c] - m1); s1 += v1[c];
        }
        float i0 = 1.f / s0, i1 = 1.f / s1;
        float acc[NC_];
#pragma unroll
        for (int c = 0; c < NC_; ++c) acc[c] = fmaxf(v0[c] * i0, v1[c] * i1);
#pragma unroll
        for (int c = 0; c < NC_; ++c) acc[c] = fmaxf(acc[c], __shfl_xor(acc[c], 1));
        if (!sub) {
            ushort h[32];
#pragma unroll
            for (int c = 0; c < NC_; ++c) { h[c] = f2bf(acc[c]); SPD(c, ll) = h[c]; }
#pragma unroll
            for (int c = NC_; c < 32; ++c) h[c] = 0;
            ushort* pt = Pt + ((size_t)b * L_ + ol) * 32;
#pragma unroll
            for (int c0 = 0; c0 < 32; c0 += 4)
                *(ushort4*)&pt[c0] = *(ushort4*)&h[c0];
        } else {
#pragma unroll
            for (int r = NC_; r < 32; ++r)
                for (int c = ll; c < 136; c += 128) SPD(r, c) = 0;
        }
    }

    // ---- MFMA1: t[l][f] = sum_c x[c][l] * w[f][c] ----
    const float* xb = x + ((size_t)b << 16);
    f32x4 acc[2][4];
#pragma unroll
    for (int i = 0; i < 2; ++i)
#pragma unroll
        for (int j = 0; j < 4; ++j) acc[i][j] = (f32x4){0.f, 0.f, 0.f, 0.f};
#pragma unroll
    for (int ks = 0; ks < 2; ++ks) {
        bf16x8 a[2];
#pragma unroll
        for (int lt = 0; lt < 2; ++lt) {
            const int l = wl0 + lt * 16 + rA;
            bf16x8 av;
#pragma unroll
            for (int j = 0; j < 8; ++j)
                av[j] = (__bf16)xb[(size_t)(ks * 32 + kg * 8 + j) * 1024 + l];
            a[lt] = av;
        }
#pragma unroll
        for (int fc = 0; fc < 4; ++fc) {
            const float* wp = w + (fc * 16 + rA) * 64 + ks * 32 + kg * 8;
            bf16x8 bv = cvt8(*(const float4*)wp, *(const float4*)(wp + 4));
            acc[0][fc] = __builtin_amdgcn_mfma_f32_16x16x32_bf16(a[0], bv, acc[0][fc], 0, 0, 0);
            acc[1][fc] = __builtin_amdgcn_mfma_f32_16x16x32_bf16(a[1], bv, acc[1][fc], 0, 0, 0);
        }
    }

    // ---- epilogue: BN + ReLU ; yb16 global ; sT [l][f] ; sTt [f][l] ----
    const float rs = 1.f / sqrtf(1.f + EPSV);
    ushort* yg = yb16 + ((size_t)b << 16);
#pragma unroll
    for (int fc = 0; fc < 4; ++fc) {
        const int f = fc * 16 + rA;
        const float sc = g[f] * rs, bb = beta[f];
#pragma unroll
        for (int lt = 0; lt < 2; ++lt) {
            ushort4 tv;
            ushort* tp = (ushort*)&tv;
#pragma unroll
            for (int r = 0; r < 4; ++r) {
                float v = relu_(sc * acc[lt][fc][r] + bb);
                tp[r] = f2bf(v);
                ST(wv, lt * 16 + kg * 4 + r, f) = tp[r];
                STT(wv, f, lt * 16 + kg * 4 + r) = tp[r];
            }
            *(ushort4*)(yg + (size_t)f * 1024 + wl0 + lt * 16 + kg * 4) = tv;
        }
    }
    __syncthreads();

    // ---- MFMA2: yw[l][f] = sum_f' t[l][f'] * w_sp[f][f'] ----
    f32x4 acc2[2][4];
#pragma unroll
    for (int i = 0; i < 2; ++i)
#pragma unroll
        for (int j = 0; j < 4; ++j) acc2[i][j] = (f32x4){0.f, 0.f, 0.f, 0.f};
#pragma unroll
    for (int kh = 0; kh < 2; ++kh) {
        bf16x8 a[2];
#pragma unroll
        for (int lt = 0; lt < 2; ++lt)
            a[lt] = *(const bf16x8*)&ST(wv, lt * 16 + rA, kh * 32 + kg * 8);
#pragma unroll
        for (int fc = 0; fc < 4; ++fc) {
            const float* wp = w_sp + (fc * 16 + rA) * 64 + kh * 32 + kg * 8;
            bf16x8 bv = cvt8(*(const float4*)wp, *(const float4*)(wp + 4));
            acc2[0][fc] = __builtin_amdgcn_mfma_f32_16x16x32_bf16(a[0], bv, acc2[0][fc], 0, 0, 0);
            acc2[1][fc] = __builtin_amdgcn_mfma_f32_16x16x32_bf16(a[1], bv, acc2[1][fc], 0, 0, 0);
        }
    }
    ushort* yp = ywb + ((size_t)b << 16);
#pragma unroll
    for (int fc = 0; fc < 4; ++fc) {
        const int f = fc * 16 + rA;
#pragma unroll
        for (int lt = 0; lt < 2; ++lt) {
            ushort4 ov;
            ov.x = f2bf(acc2[lt][fc][0]);
            ov.y = f2bf(acc2[lt][fc][1]);
            ov.z = f2bf(acc2[lt][fc][2]);
            ov.w = f2bf(acc2[lt][fc][3]);
            *(ushort4*)(yp + (size_t)f * 1024 + wl0 + lt * 16 + kg * 4) = ov;
        }
    }

    // ---- per-wave partials: U[c][f] = P·t^T, yn[c][f] = w_nc·t^T (K=32) ----
    f32x4 accU[2][4], accN[2][4];
    {
        const int lw = wv * 32 + kg * 8;
        bf16x8 aU[2], aN[2];
        aU[0] = *(const bf16x8*)&SPD(rA, lw);
        aU[1] = *(const bf16x8*)&SPD(16 + rA, lw);
        {
            const float* w0 = w_nc + (size_t)rA * 1024 + l0 + lw;
            aN[0] = cvt8(*(const float4*)w0, *(const float4*)(w0 + 4));
            if (16 + rA < NC_) {
                const float* w1 = w_nc + (size_t)(16 + rA) * 1024 + l0 + lw;
                aN[1] = cvt8(*(const float4*)w1, *(const float4*)(w1 + 4));
            } else {
                bf16x8 z;
#pragma unroll
                for (int j = 0; j < 8; ++j) z[j] = (__bf16)0.f;
                aN[1] = z;
            }
        }
#pragma unroll
        for (int i = 0; i < 2; ++i)
#pragma unroll
            for (int j = 0; j < 4; ++j) {
                accU[i][j] = (f32x4){0.f, 0.f, 0.f, 0.f};
                accN[i][j] = (f32x4){0.f, 0.f, 0.f, 0.f};
            }
#pragma unroll
        for (int nt = 0; nt < 4; ++nt) {
            bf16x8 bt = *(const bf16x8*)&STT(wv, nt * 16 + rA, kg * 8);
#pragma unroll
            for (int mt = 0; mt < 2; ++mt) {
                accU[mt][nt] = __builtin_amdgcn_mfma_f32_16x16x32_bf16(aU[mt], bt, accU[mt][nt], 0, 0, 0);
                accN[mt][nt] = __builtin_amdgcn_mfma_f32_16x16x32_bf16(aN[mt], bt, accN[mt][nt], 0, 0, 0);
            }
        }
    }

    // ---- intra-block reduce 4 waves -> 1 chunk; chunk = blk & 7 ----
    const int chunk = blk & 7;
    float* pu = partU  + ((size_t)b * NCHUNK + chunk) * (NC_ * 64);
    float* py = partYN + ((size_t)b * NCHUNK + chunk) * (NC_ * 64);
    __syncthreads();
#pragma unroll
    for (int mt = 0; mt < 2; ++mt)
#pragma unroll
        for (int r = 0; r < 4; ++r) {
            const int c = mt * 16 + kg * 4 + r;
            if (c < NC_) {
#pragma unroll
                for (int nt = 0; nt < 4; ++nt)
                    red[wv * 1728 + c * 64 + nt * 16 + rA] = accU[mt][nt][r];
            }
        }
    __syncthreads();
    for (int idx = t; idx < NC_ * 64; idx += 256)
        pu[idx] = red[idx] + red[1728 + idx] + red[2 * 1728 + idx] + red[3 * 1728 + idx];
    __syncthreads();
#pragma unroll
    for (int mt = 0; mt < 2; ++mt)
#pragma unroll
        for (int r = 0; r < 4; ++r) {
            const int c = mt * 16 + kg * 4 + r;
            if (c < NC_) {
#pragma unroll
                for (int nt = 0; nt < 4; ++nt)
                    red[wv * 1728 + c * 64 + nt * 16 + rA] = accN[mt][nt][r];
            }
        }
    __syncthreads();
    for (int idx = t; idx < NC_ * 64; idx += 256)
        py[idx] = red[idx] + red[1728 + idx] + red[2 * 1728 + idx] + red[3 * 1728 + idx];
#undef ST
#undef STT
#undef SPD
}

// ---------------- K4: reduce 8 partials; sigma = yn·w_kc^T + b_kc ; Z = sigma·U ; Zwt bf16 ----------------
__global__ void k_sigma_Z(const float* __restrict__ partYN, const float* __restrict__ partU,
                          const float* __restrict__ b_nc,
                          const float* __restrict__ w_kc, const float* __restrict__ b_kc,
                          const float* __restrict__ w_g, ushort* __restrict__ Zwt)
{
    __shared__ float syn[F_ * NC_];
    __shared__ float su[NC_ * F_];
    __shared__ float swkt[F_ * 28];
    __shared__ float ssig[NC_ * NC_];
    __shared__ float sz[NC_ * F_];
    __shared__ float swg[F_ * F_];
    const int t = threadIdx.x;          // 512
    const int b = blockIdx.x;
    for (int idx = t; idx < NC_ * F_; idx += 512) {
        int c = idx >> 6, f = idx & 63;
        float sy = 0.f, suv = 0.f;
        const float* py = partYN + ((size_t)b * NCHUNK) * (NC_ * 64) + idx;
        const float* pu = partU  + ((size_t)b * NCHUNK) * (NC_ * 64) + idx;
#pragma unroll
        for (int p = 0; p < NCHUNK; ++p) {
            sy  += py[p * (NC_ * 64)];
            suv += pu[p * (NC_ * 64)];
        }
        syn[f * NC_ + c] = sy + b_nc[c];
        su[c * F_ + f]   = suv;
    }
    for (int idx = t; idx < NC_ * F_; idx += 512) {
        int k = idx >> 6, ff = idx & 63;
        swkt[ff * 28 + k] = w_kc[idx];
    }
    for (int idx = t; idx < F_ * F_; idx += 512) swg[idx] = w_g[idx];
    __syncthreads();
    for (int idx = t; idx < NC_ * NC_; idx += 512) {
        int c = idx / NC_, k = idx - c * NC_;
        float s = b_kc[k];
        for (int ff = 0; ff < F_; ++ff)
            s = fmaf(syn[ff * NC_ + c], swkt[ff * 28 + k], s);
        ssig[c * NC_ + k] = s;
    }
    __syncthreads();
    for (int idx = t; idx < NC_ * F_; idx += 512) {
        int c = idx >> 6, ff = idx & 63;
        float s = 0.f;
        for (int k = 0; k < NC_; ++k)
            s = fmaf(ssig[c * NC_ + k], su[k * F_ + ff], s);
        sz[idx] = s;
    }
    __syncthreads();
    for (int idx = t; idx < F_ * 32; idx += 512) {
        int f = idx >> 5, c = idx & 31;
        float s = 0.f;
        if (c < NC_)
            for (int fp = 0; fp < F_; ++fp)
                s = fmaf(sz[c * F_ + fp], swg[f * F_ + fp], s);
        Zwt[(size_t)b * F_ * 32 + idx] = f2bf(s);
    }
}

// ---------------- K5: MFMA fused, 64-row tiles, global_load_lds double-buffered yw phases ----------------
__global__ __launch_bounds__(256, 4) void k_fused2(
    const ushort* __restrict__ adjb_, const ushort* __restrict__ ywb_,
    const ushort* __restrict__ Pt_, const ushort* __restrict__ Zwt_,
    const ushort* __restrict__ yb16, const float* __restrict__ b_g,
    const float* __restrict__ b_sp, const ushort* __restrict__ bwb_,
    const float* __restrict__ bn2b, float* __restrict__ out)
{
    // pool: 2 × [64 f][128 m] bf16 phase buffers (16 KB each), linear layout
    // (swizzle applied on the GLOBAL source addr + on ds_read index — m173 pattern);
    // sPre [64][68] fp32 (17408 B) aliases the pool after the main loop.
    __shared__ __align__(16) char pool[32768];
    ushort* sYW = (ushort*)pool;
    float*  sPre = (float*)pool;

    const int t = threadIdx.x;
    const int w = t >> 6, lane = t & 63;
    const int rA = lane & 15, kg = lane >> 4;
    const int fr = rA & 7;
    const int b = blockIdx.x >> 4;
    const int l0 = (blockIdx.x & 15) << 6;      // 64-row tile
    const int wl0 = l0 + w * 16;

    const __bf16* adjb = (const __bf16*)adjb_;
    const __bf16* ywb  = (const __bf16*)ywb_ + ((size_t)b << 16);
    const __bf16* Ptb  = (const __bf16*)Pt_  + ((size_t)b << 15);
    const __bf16* Zwtb = (const __bf16*)Zwt_ + ((size_t)b << 11);
    const __bf16* bwb  = (const __bf16*)bwb_;

    // stage phase p (cols p*128..+128) into buffer bufsel via global_load_lds:
    // linear LDS dest (wave-uniform base + lane*16), pre-swizzled global source.
    auto stage = [&](int p, int bufsel) {
#pragma unroll
        for (int i = 0; i < 4; ++i) {
            int idx = i * 256 + t;              // chunk 0..1023 (16B each)
            int f = idx >> 4, cm = idx & 15;
            const __bf16* src = ywb + (size_t)f * 1024 + p * 128 + ((cm ^ (f & 7)) << 3);
            __builtin_amdgcn_global_load_lds(
                (const __attribute__((address_space(1))) unsigned int*)src,
                (__attribute__((address_space(3))) unsigned int*)(sYW + bufsel * 8192 + ((i * 4 + w) << 9)),
                16, 0, 0);
        }
    };

    f32x4 accS[4];
#pragma unroll
    for (int j = 0; j < 4; ++j) accS[j] = (f32x4){0.f, 0.f, 0.f, 0.f};
    const __bf16* pa = adjb + (size_t)(wl0 + rA) * 1024 + kg * 8;

    stage(0, 0);
    __syncthreads();                            // compiler drains vmcnt before barrier

#pragma unroll 2
    for (int p = 0; p < 8; ++p) {
        const int cur = p & 1;
        if (p < 7) stage(p + 1, cur ^ 1);       // in flight during this phase's MFMA
        ushort* buf = sYW + cur * 8192;
#pragma unroll
        for (int ksl = 0; ksl < 4; ++ksl) {
            const int ks = p * 4 + ksl;
            bf16x8 a0 = *(const bf16x8*)(pa + ks * 32);
            const int ch = ((ksl * 4 + kg) ^ fr) << 3;
            bf16x8 f0 = *(const bf16x8*)&buf[(0 * 16 + rA) * 128 + ch];
            bf16x8 f1 = *(const bf16x8*)&buf[(1 * 16 + rA) * 128 + ch];
            bf16x8 f2 = *(const bf16x8*)&buf[(2 * 16 + rA) * 128 + ch];
            bf16x8 f3 = *(const bf16x8*)&buf[(3 * 16 + rA) * 128 + ch];
            accS[0] = __builtin_amdgcn_mfma_f32_16x16x32_bf16(a0, f0, accS[0], 0, 0, 0);
            accS[1] = __builtin_amdgcn_mfma_f32_16x16x32_bf16(a0, f1, accS[1], 0, 0, 0);
            accS[2] = __builtin_amdgcn_mfma_f32_16x16x32_bf16(a0, f2, accS[2], 0, 0, 0);
            accS[3] = __builtin_amdgcn_mfma_f32_16x16x32_bf16(a0, f3, accS[3], 0, 0, 0);
        }
        __syncthreads();                        // next phase's buffer now complete
    }

    // ---- dynamic path: D[l][f] = sum_c Pt[l][c] * Zwt[f][c], K=32 (c padded) ----
    f32x4 accD[4];
#pragma unroll
    for (int j = 0; j < 4; ++j) accD[j] = (f32x4){0.f, 0.f, 0.f, 0.f};
    {
        const __bf16* qa = Ptb + (size_t)(wl0 + rA) * 32 + kg * 8;
        bf16x8 a0 = *(const bf16x8*)(qa);
        const __bf16* qb = Zwtb + (size_t)rA * 32 + kg * 8;
        bf16x8 z0 = *(const bf16x8*)(qb + 0 * 512);
        bf16x8 z1 = *(const bf16x8*)(qb + 1 * 512);
        bf16x8 z2 = *(const bf16x8*)(qb + 2 * 512);
        bf16x8 z3 = *(const bf16x8*)(qb + 3 * 512);
        accD[0] = __builtin_amdgcn_mfma_f32_16x16x32_bf16(a0, z0, accD[0], 0, 0, 0);
        accD[1] = __builtin_amdgcn_mfma_f32_16x16x32_bf16(a0, z1, accD[1], 0, 0, 0);
        accD[2] = __builtin_amdgcn_mfma_f32_16x16x32_bf16(a0, z2, accD[2], 0, 0, 0);
        accD[3] = __builtin_amdgcn_mfma_f32_16x16x32_bf16(a0, z3, accD[3], 0, 0, 0);
    }

    // ---- epilogue: pre = relu(D + b_g) + relu(S + b_sp) + 3*y -> sPre [64][68] ----
    const ushort* yb = yb16 + ((size_t)b << 16);
    const int wOff = w * 16 * 68;
#pragma unroll
    for (int fc = 0; fc < 4; ++fc) {
        const int f = fc * 16 + rA;
        const float bg = b_g[f], bs = b_sp[f];
        const int lbase = wl0 + kg * 4;
        const int row = kg * 4;
        ushort4 uy = *(const ushort4*)(yb + (size_t)f * 1024 + lbase);
        const float ya[4] = {bf2f(uy.x), bf2f(uy.y), bf2f(uy.z), bf2f(uy.w)};
        f32x4 s = accS[fc], d = accD[fc];
        sPre[wOff + (row + 0) * 68 + f] = relu_(d[0] + bg) + relu_(s[0] + bs) + 3.f * ya[0];
        sPre[wOff + (row + 1) * 68 + f] = relu_(d[1] + bg) + relu_(s[1] + bs) + 3.f * ya[1];
        sPre[wOff + (row + 2) * 68 + f] = relu_(d[2] + bg) + relu_(s[2] + bs) + 3.f * ya[2];
        sPre[wOff + (row + 3) * 68 + f] = relu_(d[3] + bg) + relu_(s[3] + bs) + 3.f * ya[3];
    }
    __syncthreads();

    // ---- back conv: out[o][l] = relu( sum_f pre[l][f] * bwb[o][f] + bn2b[o] ) ----
    f32x4 accO[4];
#pragma unroll
    for (int j = 0; j < 4; ++j) accO[j] = (f32x4){0.f, 0.f, 0.f, 0.f};
#pragma unroll
    for (int kh = 0; kh < 2; ++kh) {
        const int off = wOff + rA * 68 + kh * 32 + kg * 8;
        float4 u0 = *(const float4*)&sPre[off];
        float4 u1 = *(const float4*)&sPre[off + 4];
        bf16x8 af;
        af[0] = (__bf16)u0.x; af[1] = (__bf16)u0.y; af[2] = (__bf16)u0.z; af[3] = (__bf16)u0.w;
        af[4] = (__bf16)u1.x; af[5] = (__bf16)u1.y; af[6] = (__bf16)u1.z; af[7] = (__bf16)u1.w;
#pragma unroll
        for (int oc = 0; oc < 4; ++oc) {
            bf16x8 bo = *(const bf16x8*)(bwb + oc * 1024 + (size_t)rA * 64 + kh * 32 + kg * 8);
            accO[oc] = __builtin_amdgcn_mfma_f32_16x16x32_bf16(af, bo, accO[oc], 0, 0, 0);
        }
    }
    float* ob = out + ((size_t)b << 16);
#pragma unroll
    for (int oc = 0; oc < 4; ++oc) {
        float b2v = bn2b[oc * 16 + rA];
        float4 ov = make_float4(accO[oc][0] + b2v, accO[oc][1] + b2v,
                                accO[oc][2] + b2v, accO[oc][3] + b2v);
        ov.x = relu_(ov.x); ov.y = relu_(ov.y); ov.z = relu_(ov.z); ov.w = relu_(ov.w);
        *(float4*)(ob + (size_t)(oc * 16 + rA) * 1024 + wl0 + kg * 4) = ov;
    }
}

extern "C" void kernel_launch(void* const* d_in, const int* in_sizes, int n_in,
                              void* d_out, int out_size, void* d_ws, size_t ws_size,
                              hipStream_t stream)
{
    const float* x       = (const float*)d_in[0];
    const float* SP      = (const float*)d_in[1];
    const float* trans_w = (const float*)d_in[2];
    const float* bn1_g   = (const float*)d_in[3];
    const float* bn1_b   = (const float*)d_in[4];
    const float* w_nc    = (const float*)d_in[5];
    const float* b_nc    = (const float*)d_in[6];
    const float* w_kc    = (const float*)d_in[7];
    const float* b_kc    = (const float*)d_in[8];
    const float* w_g     = (const float*)d_in[9];
    const float* b_g     = (const float*)d_in[10];
    const float* adj     = (const float*)d_in[11];
    const float* w_sp    = (const float*)d_in[12];
    const float* b_sp    = (const float*)d_in[13];
    const float* back_w  = (const float*)d_in[14];
    const float* bn2_g   = (const float*)d_in[15];
    const float* bn2_b   = (const float*)d_in[16];
    float* out = (float*)d_out;

    float* ws = (float*)d_ws;
    float* partYN = ws;                                     // [B*8][27*64] fp32
    float* partU  = partYN + (size_t)B_ * NCHUNK * NC_ * F_;// [B*8][27*64] fp32
    ushort* Pt   = (ushort*)(partU + (size_t)B_ * NCHUNK * NC_ * F_); // [64][1024][32] bf16
    ushort* Zwt  = Pt   + (size_t)B_ * L_ * 32;             // [64][64][32] bf16
    ushort* yb16 = Zwt  + (size_t)B_ * F_ * 32;             // [64][64][1024] bf16
    ushort* ywb  = yb16 + (size_t)B_ * F_ * L_;             // [64][64][1024] bf16
    ushort* adjb = ywb  + (size_t)B_ * F_ * L_;             // [1024][1024] bf16
    ushort* bwb  = adjb + (size_t)L_ * L_;                  // [64][64] bf16

    k_mega<<<1537, 256, 0, stream>>>(x, SP, trans_w, bn1_g, bn1_b, w_sp, w_nc,
                                     adj, back_w, bn2_g,
                                     Pt, yb16, ywb, partYN, partU, adjb, bwb);
    k_sigma_Z<<<64, 512, 0, stream>>>(partYN, partU, b_nc, w_kc, b_kc, w_g, Zwt);
    k_fused2<<<1024, 256, 0, stream>>>(adjb, ywb, Pt, Zwt, yb16, b_g, b_sp, bwb, bn2_b, out);
}

// Round 13
// 76.220 us; speedup vs baseline: 1.6800x; 1.0398x over previous
//
#include <hip/hip_runtime.h>

#define B_  64
#define F_  64
#define NC_ 27
#define L_  1024
#define EPSV 1e-5f
#define NCHUNK 8

typedef __bf16 bf16x8 __attribute__((ext_vector_type(8)));
typedef float  f32x4  __attribute__((ext_vector_type(4)));

static __device__ __forceinline__ float relu_(float v) { return fmaxf(v, 0.f); }
static __device__ __forceinline__ ushort f2bf(float f) {
    __bf16 h = (__bf16)f;
    ushort r;
    __builtin_memcpy(&r, &h, 2);
    return r;
}
static __device__ __forceinline__ float bf2f(ushort u) {
    __bf16 h;
    __builtin_memcpy(&h, &u, 2);
    return (float)h;
}
static __device__ __forceinline__ bf16x8 cvt8(float4 a, float4 b) {
    bf16x8 r;
    r[0] = (__bf16)a.x; r[1] = (__bf16)a.y; r[2] = (__bf16)a.z; r[3] = (__bf16)a.w;
    r[4] = (__bf16)b.x; r[5] = (__bf16)b.y; r[6] = (__bf16)b.z; r[7] = (__bf16)b.w;
    return r;
}

// ================= K_A (mega): blocks 0..511 per-(b, 128-l tile):
//   softmax+pool -> sP + Pt ; MFMA trans -> yb16 + sT/sTt ; MFMA yw -> ywb ;
//   MFMA partial U/yn -> intra-block 4-wave LDS reduce -> 1 chunk per block (NCHUNK=8)
// blocks 512..1535 : adj -> bf16 ; block 1536 : back_w*bn2_scale -> bf16
__global__ __launch_bounds__(256) void k_mega(
    const float* __restrict__ x, const float* __restrict__ SP,
    const float* __restrict__ w, const float* __restrict__ g,
    const float* __restrict__ beta, const float* __restrict__ w_sp,
    const float* __restrict__ w_nc,
    const float* __restrict__ adj, const float* __restrict__ bw,
    const float* __restrict__ g2,
    ushort* __restrict__ Pt, ushort* __restrict__ yb16, ushort* __restrict__ ywb,
    float* __restrict__ partYN, float* __restrict__ partU,
    ushort* __restrict__ adjb, ushort* __restrict__ bwb)
{
    const int blk = blockIdx.x;
    const int t = threadIdx.x;
    if (blk >= 512) {
        if (blk < 1536) {
            int i = (((blk - 512) << 8) + t) << 2;
            float4 v = *(const float4*)(adj + i);
            ushort4 o;
            o.x = f2bf(v.x); o.y = f2bf(v.y); o.z = f2bf(v.z); o.w = f2bf(v.w);
            *(ushort4*)(adjb + i) = o;
        } else {
            const float rs = 1.f / sqrtf(1.f + EPSV);
            for (int j = t; j < 4096; j += 256) {
                int o = j >> 6;
                bwb[j] = f2bf(bw[j] * g2[o] * rs);
            }
        }
        return;
    }

    __shared__ __align__(16) char pool[47616];
    ushort* sT_  = (ushort*)pool;
    ushort* sTt_ = (ushort*)(pool + 18432);
    ushort* sP_  = (ushort*)(pool + 38912);
    float*  red  = (float*)pool;
#define ST(wv_, l_, f_)  sT_[((wv_) * 32 + (l_)) * 72 + (f_)]
#define STT(wv_, f_, l_) sTt_[((wv_) * 64 + (f_)) * 40 + (l_)]
#define SPD(c_, l_)      sP_[(c_) * 136 + (l_)]

    const int wv = t >> 6, lane = t & 63;
    const int rA = lane & 15, kg = lane >> 4;
    const int b = blk >> 3;
    const int l0 = (blk & 7) << 7;
    const int wl0 = l0 + wv * 32;

    // ---- softmax + 2x2 maxpool ----
    {
        const int ll = t >> 1, sub = t & 1;
        const int ol = l0 + ll;
        const int oi = ol >> 5, oj = ol & 31;
        const float* rp = SP + (size_t)b * NC_ * 4096 + (2 * oi + sub) * 64 + 2 * oj;
        float v0[NC_], v1[NC_];
        float m0 = -1e30f, m1 = -1e30f;
#pragma unroll
        for (int c = 0; c < NC_; ++c) {
            float2 v = *(const float2*)(rp + c * 4096);
            v0[c] = v.x; v1[c] = v.y;
            m0 = fmaxf(m0, v.x); m1 = fmaxf(m1, v.y);
        }
        float s0 = 0.f, s1 = 0.f;
#pragma unroll
        for (int c = 0; c < NC_; ++c) {
            v0[c] = __expf(v0[c] - m0); s0 += v0[c];
            v1[c] = __expf(v1[c] - m1); s1 += v1[c];
        }
        float i0 = 1.f / s0, i1 = 1.f / s1;
        float acc[NC_];
#pragma unroll
        for (int c = 0; c < NC_; ++c) acc[c] = fmaxf(v0[c] * i0, v1[c] * i1);
#pragma unroll
        for (int c = 0; c < NC_; ++c) acc[c] = fmaxf(acc[c], __shfl_xor(acc[c], 1));
        if (!sub) {
            ushort h[32];
#pragma unroll
            for (int c = 0; c < NC_; ++c) { h[c] = f2bf(acc[c]); SPD(c, ll) = h[c]; }
#pragma unroll
            for (int c = NC_; c < 32; ++c) h[c] = 0;
            ushort* pt = Pt + ((size_t)b * L_ + ol) * 32;
#pragma unroll
            for (int c0 = 0; c0 < 32; c0 += 4)
                *(ushort4*)&pt[c0] = *(ushort4*)&h[c0];
        } else {
#pragma unroll
            for (int r = NC_; r < 32; ++r)
                for (int c = ll; c < 136; c += 128) SPD(r, c) = 0;
        }
    }

    // ---- MFMA1: t[l][f] = sum_c x[c][l] * w[f][c] ----
    const float* xb = x + ((size_t)b << 16);
    f32x4 acc[2][4];
#pragma unroll
    for (int i = 0; i < 2; ++i)
#pragma unroll
        for (int j = 0; j < 4; ++j) acc[i][j] = (f32x4){0.f, 0.f, 0.f, 0.f};
#pragma unroll
    for (int ks = 0; ks < 2; ++ks) {
        bf16x8 a[2];
#pragma unroll
        for (int lt = 0; lt < 2; ++lt) {
            const int l = wl0 + lt * 16 + rA;
            bf16x8 av;
#pragma unroll
            for (int j = 0; j < 8; ++j)
                av[j] = (__bf16)xb[(size_t)(ks * 32 + kg * 8 + j) * 1024 + l];
            a[lt] = av;
        }
#pragma unroll
        for (int fc = 0; fc < 4; ++fc) {
            const float* wp = w + (fc * 16 + rA) * 64 + ks * 32 + kg * 8;
            bf16x8 bv = cvt8(*(const float4*)wp, *(const float4*)(wp + 4));
            acc[0][fc] = __builtin_amdgcn_mfma_f32_16x16x32_bf16(a[0], bv, acc[0][fc], 0, 0, 0);
            acc[1][fc] = __builtin_amdgcn_mfma_f32_16x16x32_bf16(a[1], bv, acc[1][fc], 0, 0, 0);
        }
    }

    // ---- epilogue: BN + ReLU ; yb16 global ; sT [l][f] ; sTt [f][l] ----
    const float rs = 1.f / sqrtf(1.f + EPSV);
    ushort* yg = yb16 + ((size_t)b << 16);
#pragma unroll
    for (int fc = 0; fc < 4; ++fc) {
        const int f = fc * 16 + rA;
        const float sc = g[f] * rs, bb = beta[f];
#pragma unroll
        for (int lt = 0; lt < 2; ++lt) {
            ushort4 tv;
            ushort* tp = (ushort*)&tv;
#pragma unroll
            for (int r = 0; r < 4; ++r) {
                float v = relu_(sc * acc[lt][fc][r] + bb);
                tp[r] = f2bf(v);
                ST(wv, lt * 16 + kg * 4 + r, f) = tp[r];
                STT(wv, f, lt * 16 + kg * 4 + r) = tp[r];
            }
            *(ushort4*)(yg + (size_t)f * 1024 + wl0 + lt * 16 + kg * 4) = tv;
        }
    }
    __syncthreads();

    // ---- MFMA2: yw[l][f] = sum_f' t[l][f'] * w_sp[f][f'] ----
    f32x4 acc2[2][4];
#pragma unroll
    for (int i = 0; i < 2; ++i)
#pragma unroll
        for (int j = 0; j < 4; ++j) acc2[i][j] = (f32x4){0.f, 0.f, 0.f, 0.f};
#pragma unroll
    for (int kh = 0; kh < 2; ++kh) {
        bf16x8 a[2];
#pragma unroll
        for (int lt = 0; lt < 2; ++lt)
            a[lt] = *(const bf16x8*)&ST(wv, lt * 16 + rA, kh * 32 + kg * 8);
#pragma unroll
        for (int fc = 0; fc < 4; ++fc) {
            const float* wp = w_sp + (fc * 16 + rA) * 64 + kh * 32 + kg * 8;
            bf16x8 bv = cvt8(*(const float4*)wp, *(const float4*)(wp + 4));
            acc2[0][fc] = __builtin_amdgcn_mfma_f32_16x16x32_bf16(a[0], bv, acc2[0][fc], 0, 0, 0);
            acc2[1][fc] = __builtin_amdgcn_mfma_f32_16x16x32_bf16(a[1], bv, acc2[1][fc], 0, 0, 0);
        }
    }
    ushort* yp = ywb + ((size_t)b << 16);
#pragma unroll
    for (int fc = 0; fc < 4; ++fc) {
        const int f = fc * 16 + rA;
#pragma unroll
        for (int lt = 0; lt < 2; ++lt) {
            ushort4 ov;
            ov.x = f2bf(acc2[lt][fc][0]);
            ov.y = f2bf(acc2[lt][fc][1]);
            ov.z = f2bf(acc2[lt][fc][2]);
            ov.w = f2bf(acc2[lt][fc][3]);
            *(ushort4*)(yp + (size_t)f * 1024 + wl0 + lt * 16 + kg * 4) = ov;
        }
    }

    // ---- per-wave partials: U[c][f] = P·t^T, yn[c][f] = w_nc·t^T (K=32) ----
    f32x4 accU[2][4], accN[2][4];
    {
        const int lw = wv * 32 + kg * 8;
        bf16x8 aU[2], aN[2];
        aU[0] = *(const bf16x8*)&SPD(rA, lw);
        aU[1] = *(const bf16x8*)&SPD(16 + rA, lw);
        {
            const float* w0 = w_nc + (size_t)rA * 1024 + l0 + lw;
            aN[0] = cvt8(*(const float4*)w0, *(const float4*)(w0 + 4));
            if (16 + rA < NC_) {
                const float* w1 = w_nc + (size_t)(16 + rA) * 1024 + l0 + lw;
                aN[1] = cvt8(*(const float4*)w1, *(const float4*)(w1 + 4));
            } else {
                bf16x8 z;
#pragma unroll
                for (int j = 0; j < 8; ++j) z[j] = (__bf16)0.f;
                aN[1] = z;
            }
        }
#pragma unroll
        for (int i = 0; i < 2; ++i)
#pragma unroll
            for (int j = 0; j < 4; ++j) {
                accU[i][j] = (f32x4){0.f, 0.f, 0.f, 0.f};
                accN[i][j] = (f32x4){0.f, 0.f, 0.f, 0.f};
            }
#pragma unroll
        for (int nt = 0; nt < 4; ++nt) {
            bf16x8 bt = *(const bf16x8*)&STT(wv, nt * 16 + rA, kg * 8);
#pragma unroll
            for (int mt = 0; mt < 2; ++mt) {
                accU[mt][nt] = __builtin_amdgcn_mfma_f32_16x16x32_bf16(aU[mt], bt, accU[mt][nt], 0, 0, 0);
                accN[mt][nt] = __builtin_amdgcn_mfma_f32_16x16x32_bf16(aN[mt], bt, accN[mt][nt], 0, 0, 0);
            }
        }
    }

    // ---- intra-block reduce 4 waves -> 1 chunk; chunk = blk & 7 ----
    const int chunk = blk & 7;
    float* pu = partU  + ((size_t)b * NCHUNK + chunk) * (NC_ * 64);
    float* py = partYN + ((size_t)b * NCHUNK + chunk) * (NC_ * 64);
    __syncthreads();
#pragma unroll
    for (int mt = 0; mt < 2; ++mt)
#pragma unroll
        for (int r = 0; r < 4; ++r) {
            const int c = mt * 16 + kg * 4 + r;
            if (c < NC_) {
#pragma unroll
                for (int nt = 0; nt < 4; ++nt)
                    red[wv * 1728 + c * 64 + nt * 16 + rA] = accU[mt][nt][r];
            }
        }
    __syncthreads();
    for (int idx = t; idx < NC_ * 64; idx += 256)
        pu[idx] = red[idx] + red[1728 + idx] + red[2 * 1728 + idx] + red[3 * 1728 + idx];
    __syncthreads();
#pragma unroll
    for (int mt = 0; mt < 2; ++mt)
#pragma unroll
        for (int r = 0; r < 4; ++r) {
            const int c = mt * 16 + kg * 4 + r;
            if (c < NC_) {
#pragma unroll
                for (int nt = 0; nt < 4; ++nt)
                    red[wv * 1728 + c * 64 + nt * 16 + rA] = accN[mt][nt][r];
            }
        }
    __syncthreads();
    for (int idx = t; idx < NC_ * 64; idx += 256)
        py[idx] = red[idx] + red[1728 + idx] + red[2 * 1728 + idx] + red[3 * 1728 + idx];
#undef ST
#undef STT
#undef SPD
}

// ---------------- K4: reduce 8 partials; sigma = yn·w_kc^T + b_kc ; Z = sigma·U ; Zwt bf16 ----------------
__global__ void k_sigma_Z(const float* __restrict__ partYN, const float* __restrict__ partU,
                          const float* __restrict__ b_nc,
                          const float* __restrict__ w_kc, const float* __restrict__ b_kc,
                          const float* __restrict__ w_g, ushort* __restrict__ Zwt)
{
    __shared__ float syn[F_ * NC_];
    __shared__ float su[NC_ * F_];
    __shared__ float swkt[F_ * 28];
    __shared__ float ssig[NC_ * NC_];
    __shared__ float sz[NC_ * F_];
    __shared__ float swg[F_ * F_];
    const int t = threadIdx.x;          // 512
    const int b = blockIdx.x;
    for (int idx = t; idx < NC_ * F_; idx += 512) {
        int c = idx >> 6, f = idx & 63;
        float sy = 0.f, suv = 0.f;
        const float* py = partYN + ((size_t)b * NCHUNK) * (NC_ * 64) + idx;
        const float* pu = partU  + ((size_t)b * NCHUNK) * (NC_ * 64) + idx;
#pragma unroll
        for (int p = 0; p < NCHUNK; ++p) {
            sy  += py[p * (NC_ * 64)];
            suv += pu[p * (NC_ * 64)];
        }
        syn[f * NC_ + c] = sy + b_nc[c];
        su[c * F_ + f]   = suv;
    }
    for (int idx = t; idx < NC_ * F_; idx += 512) {
        int k = idx >> 6, ff = idx & 63;
        swkt[ff * 28 + k] = w_kc[idx];
    }
    for (int idx = t; idx < F_ * F_; idx += 512) swg[idx] = w_g[idx];
    __syncthreads();
    for (int idx = t; idx < NC_ * NC_; idx += 512) {
        int c = idx / NC_, k = idx - c * NC_;
        float s = b_kc[k];
        for (int ff = 0; ff < F_; ++ff)
            s = fmaf(syn[ff * NC_ + c], swkt[ff * 28 + k], s);
        ssig[c * NC_ + k] = s;
    }
    __syncthreads();
    for (int idx = t; idx < NC_ * F_; idx += 512) {
        int c = idx >> 6, ff = idx & 63;
        float s = 0.f;
        for (int k = 0; k < NC_; ++k)
            s = fmaf(ssig[c * NC_ + k], su[k * F_ + ff], s);
        sz[idx] = s;
    }
    __syncthreads();
    for (int idx = t; idx < F_ * 32; idx += 512) {
        int f = idx >> 5, c = idx & 31;
        float s = 0.f;
        if (c < NC_)
            for (int fp = 0; fp < F_; ++fp)
                s = fmaf(sz[c * F_ + fp], swg[f * F_ + fp], s);
        Zwt[(size_t)b * F_ * 32 + idx] = f2bf(s);
    }
}

// ---------------- K5: MFMA fused, 64-row tiles, quarter-staged yw, 4 blocks/CU, XCD-swizzled ----------------
__global__ __launch_bounds__(256, 4) void k_fused2(
    const ushort* __restrict__ adjb_, const ushort* __restrict__ ywb_,
    const ushort* __restrict__ Pt_, const ushort* __restrict__ Zwt_,
    const ushort* __restrict__ yb16, const float* __restrict__ b_g,
    const float* __restrict__ b_sp, const ushort* __restrict__ bwb_,
    const float* __restrict__ bn2b, float* __restrict__ out)
{
    // pool: sYW [64 f][256 m] bf16 quarter (32 KB), swizzled chunks;
    // reused afterwards as sPre [64][68] fp32 (17408 B).
    __shared__ __align__(16) char pool[32768];
    ushort* sYW = (ushort*)pool;
    float*  sPre = (float*)pool;

    const int t = threadIdx.x;
    const int w = t >> 6, lane = t & 63;
    const int rA = lane & 15, kg = lane >> 4;
    const int fr = rA & 7;
    // T1 XCD swizzle (bijective: grid 1024 % 8 == 0): all 16 l-tiles of a batch —
    // and 8 whole batches — land on one XCD, so yw/adj panels live in its local L2.
    const int swz = (blockIdx.x & 7) * 128 + (blockIdx.x >> 3);
    const int b = swz >> 4;
    const int l0 = (swz & 15) << 6;             // 64-row tile
    const int wl0 = l0 + w * 16;                // this wave's 16 rows

    const __bf16* adjb = (const __bf16*)adjb_;
    const __bf16* ywb  = (const __bf16*)ywb_ + ((size_t)b << 16);
    const __bf16* Ptb  = (const __bf16*)Pt_  + ((size_t)b << 15);
    const __bf16* Zwtb = (const __bf16*)Zwt_ + ((size_t)b << 11);
    const __bf16* bwb  = (const __bf16*)bwb_;

    f32x4 accS[4];
#pragma unroll
    for (int j = 0; j < 4; ++j) accS[j] = (f32x4){0.f, 0.f, 0.f, 0.f};

    const __bf16* pa = adjb + (size_t)(wl0 + rA) * 1024 + kg * 8;

    bf16x8 st[8];
    // prologue: stage quarter 0 (cols 0..255)
#pragma unroll
    for (int i = 0; i < 8; ++i) {
        int idx = i * 256 + t;                  // 0..2047
        int f = idx >> 5, cm = idx & 31;
        st[i] = *(const bf16x8*)(ywb + (size_t)f * 1024 + cm * 8);
    }
#pragma unroll
    for (int i = 0; i < 8; ++i) {
        int idx = i * 256 + t;
        int f = idx >> 5, cm = idx & 31;
        *(bf16x8*)&sYW[f * 256 + ((cm ^ (f & 7)) << 3)] = st[i];
    }
    __syncthreads();

#pragma unroll
    for (int q = 0; q < 4; ++q) {
        if (q < 3) {
            // prefetch next quarter into registers (latency hides under MFMA)
#pragma unroll
            for (int i = 0; i < 8; ++i) {
                int idx = i * 256 + t;
                int f = idx >> 5, cm = idx & 31;
                st[i] = *(const bf16x8*)(ywb + (size_t)f * 1024 + (q + 1) * 256 + cm * 8);
            }
        }
#pragma unroll
        for (int ksl = 0; ksl < 8; ++ksl) {
            const int ks = q * 8 + ksl;
            bf16x8 a0 = *(const bf16x8*)(pa + ks * 32);
            const int ch = ((ksl * 4 + kg) ^ fr) << 3;
            bf16x8 f0 = *(const bf16x8*)&sYW[(0 * 16 + rA) * 256 + ch];
            bf16x8 f1 = *(const bf16x8*)&sYW[(1 * 16 + rA) * 256 + ch];
            bf16x8 f2 = *(const bf16x8*)&sYW[(2 * 16 + rA) * 256 + ch];
            bf16x8 f3 = *(const bf16x8*)&sYW[(3 * 16 + rA) * 256 + ch];
            accS[0] = __builtin_amdgcn_mfma_f32_16x16x32_bf16(a0, f0, accS[0], 0, 0, 0);
            accS[1] = __builtin_amdgcn_mfma_f32_16x16x32_bf16(a0, f1, accS[1], 0, 0, 0);
            accS[2] = __builtin_amdgcn_mfma_f32_16x16x32_bf16(a0, f2, accS[2], 0, 0, 0);
            accS[3] = __builtin_amdgcn_mfma_f32_16x16x32_bf16(a0, f3, accS[3], 0, 0, 0);
        }
        __syncthreads();
        if (q < 3) {
#pragma unroll
            for (int i = 0; i < 8; ++i) {
                int idx = i * 256 + t;
                int f = idx >> 5, cm = idx & 31;
                *(bf16x8*)&sYW[f * 256 + ((cm ^ (f & 7)) << 3)] = st[i];
            }
            __syncthreads();
        }
    }

    // dynamic path: D[l][f] = sum_c Pt[l][c] * Zwt[f][c], K=32 (c padded)
    f32x4 accD[4];
#pragma unroll
    for (int j = 0; j < 4; ++j) accD[j] = (f32x4){0.f, 0.f, 0.f, 0.f};
    {
        const __bf16* qa = Ptb + (size_t)(wl0 + rA) * 32 + kg * 8;
        bf16x8 a0 = *(const bf16x8*)(qa);
        const __bf16* qb = Zwtb + (size_t)rA * 32 + kg * 8;
        bf16x8 z0 = *(const bf16x8*)(qb + 0 * 512);
        bf16x8 z1 = *(const bf16x8*)(qb + 1 * 512);
        bf16x8 z2 = *(const bf16x8*)(qb + 2 * 512);
        bf16x8 z3 = *(const bf16x8*)(qb + 3 * 512);
        accD[0] = __builtin_amdgcn_mfma_f32_16x16x32_bf16(a0, z0, accD[0], 0, 0, 0);
        accD[1] = __builtin_amdgcn_mfma_f32_16x16x32_bf16(a0, z1, accD[1], 0, 0, 0);
        accD[2] = __builtin_amdgcn_mfma_f32_16x16x32_bf16(a0, z2, accD[2], 0, 0, 0);
        accD[3] = __builtin_amdgcn_mfma_f32_16x16x32_bf16(a0, z3, accD[3], 0, 0, 0);
    }

    // epilogue: pre = relu(D + b_g) + relu(S + b_sp) + 3*y -> sPre [64][68] fp32
    const ushort* yb = yb16 + ((size_t)b << 16);
    const int wOff = w * 16 * 68;
#pragma unroll
    for (int fc = 0; fc < 4; ++fc) {
        const int f = fc * 16 + rA;
        const float bg = b_g[f], bs = b_sp[f];
        const int lbase = wl0 + kg * 4;
        const int row = kg * 4;
        ushort4 uy = *(const ushort4*)(yb + (size_t)f * 1024 + lbase);
        const float ya[4] = {bf2f(uy.x), bf2f(uy.y), bf2f(uy.z), bf2f(uy.w)};
        f32x4 s = accS[fc], d = accD[fc];
        sPre[wOff + (row + 0) * 68 + f] = relu_(d[0] + bg) + relu_(s[0] + bs) + 3.f * ya[0];
        sPre[wOff + (row + 1) * 68 + f] = relu_(d[1] + bg) + relu_(s[1] + bs) + 3.f * ya[1];
        sPre[wOff + (row + 2) * 68 + f] = relu_(d[2] + bg) + relu_(s[2] + bs) + 3.f * ya[2];
        sPre[wOff + (row + 3) * 68 + f] = relu_(d[3] + bg) + relu_(s[3] + bs) + 3.f * ya[3];
    }
    __syncthreads();

    // back conv: out[o][l] = relu( sum_f pre[l][f] * bwb[o][f] + bn2b[o] )
    f32x4 accO[4];
#pragma unroll
    for (int j = 0; j < 4; ++j) accO[j] = (f32x4){0.f, 0.f, 0.f, 0.f};
#pragma unroll
    for (int kh = 0; kh < 2; ++kh) {
        const int off = wOff + rA * 68 + kh * 32 + kg * 8;
        float4 u0 = *(const float4*)&sPre[off];
        float4 u1 = *(const float4*)&sPre[off + 4];
        bf16x8 af;
        af[0] = (__bf16)u0.x; af[1] = (__bf16)u0.y; af[2] = (__bf16)u0.z; af[3] = (__bf16)u0.w;
        af[4] = (__bf16)u1.x; af[5] = (__bf16)u1.y; af[6] = (__bf16)u1.z; af[7] = (__bf16)u1.w;
#pragma unroll
        for (int oc = 0; oc < 4; ++oc) {
            bf16x8 bo = *(const bf16x8*)(bwb + oc * 1024 + (size_t)rA * 64 + kh * 32 + kg * 8);
            accO[oc] = __builtin_amdgcn_mfma_f32_16x16x32_bf16(af, bo, accO[oc], 0, 0, 0);
        }
    }
    float* ob = out + ((size_t)b << 16);
#pragma unroll
    for (int oc = 0; oc < 4; ++oc) {
        float b2v = bn2b[oc * 16 + rA];
        float4 ov = make_float4(accO[oc][0] + b2v, accO[oc][1] + b2v,
                                accO[oc][2] + b2v, accO[oc][3] + b2v);
        ov.x = relu_(ov.x); ov.y = relu_(ov.y); ov.z = relu_(ov.z); ov.w = relu_(ov.w);
        *(float4*)(ob + (size_t)(oc * 16 + rA) * 1024 + wl0 + kg * 4) = ov;
    }
}

extern "C" void kernel_launch(void* const* d_in, const int* in_sizes, int n_in,
                              void* d_out, int out_size, void* d_ws, size_t ws_size,
                              hipStream_t stream)
{
    const float* x       = (const float*)d_in[0];
    const float* SP      = (const float*)d_in[1];
    const float* trans_w = (const float*)d_in[2];
    const float* bn1_g   = (const float*)d_in[3];
    const float* bn1_b   = (const float*)d_in[4];
    const float* w_nc    = (const float*)d_in[5];
    const float* b_nc    = (const float*)d_in[6];
    const float* w_kc    = (const float*)d_in[7];
    const float* b_kc    = (const float*)d_in[8];
    const float* w_g     = (const float*)d_in[9];
    const float* b_g     = (const float*)d_in[10];
    const float* adj     = (const float*)d_in[11];
    const float* w_sp    = (const float*)d_in[12];
    const float* b_sp    = (const float*)d_in[13];
    const float* back_w  = (const float*)d_in[14];
    const float* bn2_g   = (const float*)d_in[15];
    const float* bn2_b   = (const float*)d_in[16];
    float* out = (float*)d_out;

    float* ws = (float*)d_ws;
    float* partYN = ws;                                     // [B*8][27*64] fp32
    float* partU  = partYN + (size_t)B_ * NCHUNK * NC_ * F_;// [B*8][27*64] fp32
    ushort* Pt   = (ushort*)(partU + (size_t)B_ * NCHUNK * NC_ * F_); // [64][1024][32] bf16
    ushort* Zwt  = Pt   + (size_t)B_ * L_ * 32;             // [64][64][32] bf16
    ushort* yb16 = Zwt  + (size_t)B_ * F_ * 32;             // [64][64][1024] bf16
    ushort* ywb  = yb16 + (size_t)B_ * F_ * L_;             // [64][64][1024] bf16
    ushort* adjb = ywb  + (size_t)B_ * F_ * L_;             // [1024][1024] bf16
    ushort* bwb  = adjb + (size_t)L_ * L_;                  // [64][64] bf16

    k_mega<<<1537, 256, 0, stream>>>(x, SP, trans_w, bn1_g, bn1_b, w_sp, w_nc,
                                     adj, back_w, bn2_g,
                                     Pt, yb16, ywb, partYN, partU, adjb, bwb);
    k_sigma_Z<<<64, 512, 0, stream>>>(partYN, partU, b_nc, w_kc, b_kc, w_g, Zwt);
    k_fused2<<<1024, 256, 0, stream>>>(adjb, ywb, Pt, Zwt, yb16, b_g, b_sp, bwb, bn2_b, out);
}